// Round 8
// baseline (504.964 us; speedup 1.0000x reference)
//
#include <hip/hip_runtime.h>
#include <stdint.h>

#define IN_F  4096
#define OUT_F 4096
#define MROWS 8192            // 4 * 2048

typedef __bf16 bf16x8 __attribute__((ext_vector_type(8)));
typedef float  f32x4  __attribute__((ext_vector_type(4)));

// ---------------- numeric helpers (replicate reference rounding) -----------

__device__ __forceinline__ float e4m3_round_dev(float x) {
    x = fminf(x, 448.0f);                 // x >= 0 by construction (amax)
    float lo, hi;
    if (x < 0.015625f) {                  // below 2^-6: denormal grid, step 2^-9
        lo = floorf(x * 512.0f) * 0.001953125f;
        hi = lo + 0.001953125f;
    } else {
        unsigned u = __float_as_uint(x);
        int E = (int)((u >> 23) & 0xFF) - 127;                    // 2^E <= x < 2^(E+1)
        float step  = __uint_as_float((unsigned)(E + 124) << 23); // 2^(E-3)
        float istep = __uint_as_float((unsigned)(130 - E) << 23); // 2^(3-E), exact
        lo = floorf(x * istep) * step;    // exact pow2 scaling
        hi = lo + step;
    }
    return (x - lo <= hi - x) ? lo : hi;
}

__device__ __forceinline__ float e4m3_decode_dev(int bits) {
    int e = (bits >> 3) & 15;
    int m = bits & 7;
    float mag;
    if (e == 0) mag = (float)m * 0.001953125f;  // m/8 * 2^-6
    else        mag = (1.0f + (float)m * 0.125f) * __uint_as_float((unsigned)(e + 120) << 23); // 2^(e-7)
    return (bits & 0x80) ? -mag : mag;
}

__device__ __forceinline__ float fp4_round_dev(float y) {
    float a = fminf(fabsf(y), 6.0f);
    float v;
    if (a < 1.75f) {
        if (a < 0.75f) v = (a < 0.25f) ? 0.0f : 0.5f;
        else           v = (a < 1.25f) ? 1.0f : 1.5f;
    } else {
        if (a < 3.5f)  v = (a < 2.5f) ? 2.0f : 3.0f;
        else           v = (a < 5.0f) ? 4.0f : 6.0f;
    }
    return copysignf(v, y);
}

__device__ __forceinline__ float fp4_decode_dev(int c) {
    int e = (c >> 1) & 3, m = c & 1;
    float mag = (e == 0) ? 0.5f * (float)m
                         : (1.0f + 0.5f * (float)m) * __uint_as_float((unsigned)(e + 126) << 23); // 2^(e-1)
    return (c & 8) ? -mag : mag;
}

__device__ __forceinline__ unsigned pack_bf16x2(float a, float b) {
    return (__float_as_uint(a) >> 16) | ((__float_as_uint(b) >> 16) << 16);
}

// ---------------- kernel 1: activation quant-dequant (verified) ------------
__global__ __launch_bounds__(256) void quant_act_kernel(
    const float* __restrict__ x, const float* __restrict__ in_scale,
    unsigned short* __restrict__ Aq)
{
    int t = blockIdx.x * 256 + threadIdx.x;   // thread id; 4 elems each
    const float isc = in_scale[0];
    float4 v = ((const float4*)x)[t];

    float a = fmaxf(fmaxf(fabsf(v.x), fabsf(v.y)), fmaxf(fabsf(v.z), fabsf(v.w)));
    a = fmaxf(a, __shfl_xor(a, 1));
    a = fmaxf(a, __shfl_xor(a, 2));           // group (4 lanes) amax

    float bscale = e4m3_round_dev(a / (6.0f * isc));  // IEEE div, as reference
    float eff = bscale * isc;
    float safe = (eff > 0.0f) ? eff : 1.0f;
    float inv = 1.0f / safe;                          // IEEE div

    unsigned o0 = pack_bf16x2(fp4_round_dev(v.x * inv) * bscale,
                              fp4_round_dev(v.y * inv) * bscale);
    unsigned o1 = pack_bf16x2(fp4_round_dev(v.z * inv) * bscale,
                              fp4_round_dev(v.w * inv) * bscale);
    ((uint2*)Aq)[t] = make_uint2(o0, o1);
}

// ---------------- kernel 2: weight dequant (verified) ----------------------
__global__ __launch_bounds__(256) void dequant_w_kernel(
    const int* __restrict__ wq, const int* __restrict__ wsb,
    unsigned short* __restrict__ Wd)
{
    int t = blockIdx.x * 256 + threadIdx.x;
    float scale = e4m3_decode_dev(wsb[t >> 1]);
    int4 b = ((const int4*)wq)[t];
    int bytes[4] = { b.x, b.y, b.z, b.w };
    unsigned out[4];
    #pragma unroll
    for (int i = 0; i < 4; i++) {
        int by = bytes[i];
        float v0 = fp4_decode_dev(by & 15) * scale;
        float v1 = fp4_decode_dev((by >> 4) & 15) * scale;
        out[i] = pack_bf16x2(v0, v1);
    }
    ((uint4*)Wd)[t] = make_uint4(out[0], out[1], out[2], out[3]);
}

// ---------------- kernel 3: bf16 GEMM, 128x256 tile, 2 blocks/CU -----------
//
// C[m,n] = s * sum_k A'[m,k] * W'[n,k],  s = input_scale * ws2
//
// 256 threads = 4 waves (wn 0..3), wave tile 128x64 (unchanged -> per-FLOP
// LDS traffic identical to the 256^2 kernel). BK=32, LDS 48 KiB/block:
//   [A par0 8K | A par1 8K | B par0 16K | B par1 16K]
// => with ~248 regs/wave, exactly TWO blocks co-reside per CU (1 wave of
// each block per SIMD). The two blocks form independent barrier domains:
// when one drains vmcnt/barrier, the other's waves keep the MFMA pipe fed.
// This attacks the ~1400 cyc/K-tile residual the single-block 256^2 design
// exposed (R3/R7: 4181 cyc vs 2483 MFMA + ~2760 LDS floors).
//
// Per K-tile t (par = t&1), 2 phases, 1 barrier each:
//   ph0: read af_lo(4)+bf(4) | stage ALL of t+1 (B: 4, A: 2 gloads) |
//        BARRIER | MFMA m0..3 x n0..3 (16)
//   ph1: read af_hi(4) | vmcnt(0) | BARRIER | MFMA m4..7 x n0..3 (16)
// RAW: the single vmcnt(0)+barrier at ph1(t) covers all 6 stages of t+1
// before any ph0(t+1) read. No counted vmcnt anywhere.
// WAR: A[par^1] last read ph1(t-1) (issued pre-barrier, executes ~150 cyc);
// overwriting DMA issues post-barrier and lands >=~1300 cyc later (HBM
// latency) -- same distance R3 validated. B[par^1] last read ph0(t-1),
// overwrite issues ph0(t): 2 barriers later.
//
// LDS swizzle (re-derived for 4-chunk/64B rows): chunk j of row holds
// k-chunk kc = j ^ ((row>>1)&3). Read slot j = quad ^ ((l16>>1)&3) spreads
// 16 lanes over all 32 banks (2-way aliasing = free). NOTE: the old
// (row&3) XOR would leave l16={0,4,8,12} on the same bank (4-way).
// Accumulation order per acc element is bitwise-identical to R3/R7
// (same K-chunk sequence, k ascending in 32-chunks).

__device__ __forceinline__ void gload16(const void* g, void* l) {
    __builtin_amdgcn_global_load_lds((__attribute__((address_space(1))) void*)g,
                                     (__attribute__((address_space(3))) void*)l,
                                     16, 0, 0);
}

#define BARRIER() __builtin_amdgcn_s_barrier()
#define FENCE() asm volatile("" ::: "memory")
#define WAIT_VM(n) asm volatile("s_waitcnt vmcnt(" #n ")" ::: "memory")

// stage A(t+dt) into parity par: 2 chunks/thread (rows tid>>2, +64)
#define STAGE_A(par, dt) do {                                                  \
    const unsigned short* g_ = gA0 + (dt) * 32;                                \
    char* l_ = ldsb + (par) * 8192 + tid * 16;                                 \
    gload16(g_,              l_);                                              \
    gload16(g_ + 64 * IN_F,  l_ + 4096);                                       \
} while (0)

// stage B(t+dt): 4 chunks/thread (rows tid>>2, +64, +128, +192)
#define STAGE_B(par, dt) do {                                                  \
    const unsigned short* g_ = gB0 + (dt) * 32;                                \
    char* l_ = ldsb + 16384 + (par) * 16384 + tid * 16;                        \
    gload16(g_,               l_);                                             \
    gload16(g_ + 64  * IN_F,  l_ + 4096);                                      \
    gload16(g_ + 128 * IN_F,  l_ + 8192);                                      \
    gload16(g_ + 192 * IN_F,  l_ + 12288);                                     \
} while (0)

// af[m_] <- A rows (qm*64 + m_*16 + l16), k-chunk quad (swizzled slot)
#define LOADAF(par, qm) do {                                                   \
    const char* pa_ = ldsb + (par) * 8192 + (qm) * 4096 + aBase;               \
    _Pragma("unroll") for (int m_ = 0; m_ < 4; ++m_)                           \
        af[m_] = *(const bf16x8*)(pa_ + m_ * 1024);                            \
} while (0)

// bf[n_] <- B rows (wn*64 + n_*16 + l16)
#define LOADBF(par) do {                                                       \
    const char* pb_ = ldsb + 16384 + (par) * 16384 + bBase;                    \
    _Pragma("unroll") for (int n_ = 0; n_ < 4; ++n_)                           \
        bf[n_] = *(const bf16x8*)(pb_ + n_ * 1024);                            \
} while (0)

#define MFMAQ(qm) do {                                                         \
    __builtin_amdgcn_s_setprio(1);                                             \
    _Pragma("unroll") for (int m_ = 0; m_ < 4; ++m_)                           \
      _Pragma("unroll") for (int n_ = 0; n_ < 4; ++n_)                         \
          acc[(qm)*4 + m_][n_] =                                               \
            __builtin_amdgcn_mfma_f32_16x16x32_bf16(                           \
              af[m_], bf[n_], acc[(qm)*4 + m_][n_], 0, 0, 0);                  \
    __builtin_amdgcn_s_setprio(0);                                             \
} while (0)

// One K-tile, 2 phases, 1 barrier each. SN: stage tile t+1. VM: drain.
#define KTILE(par, DT, SN, VM) do {                                            \
    /* ph0 */                                                                  \
    LOADAF(par, 0); LOADBF(par);                                               \
    if (SN) { STAGE_B((par) ^ 1, (DT) + 1); STAGE_A((par) ^ 1, (DT) + 1); }    \
    BARRIER(); FENCE();                                                        \
    MFMAQ(0);                                                                  \
    /* ph1 */                                                                  \
    LOADAF(par, 1);                                                            \
    if (VM) { WAIT_VM(0); }                                                    \
    BARRIER(); FENCE();                                                        \
    MFMAQ(1);                                                                  \
} while (0)

__global__ __launch_bounds__(256, 2) void gemm128x256(
    const unsigned short* __restrict__ A, const unsigned short* __restrict__ B,
    float* __restrict__ C, const float* __restrict__ isc,
    const float* __restrict__ ws2)
{
    extern __shared__ __align__(16) char lds[];
    char* const ldsb = lds;

    const int tid  = threadIdx.x;
    const int lane = tid & 63;
    const int wn   = tid >> 6;          // 0..3 (N quarter)

    // XCD-bijective swizzle: 1024 blocks, 8 XCDs, 128 contiguous per XCD.
    // Within an XCD: bm fastest -> consecutive blocks share the bn B-panel
    // (2 MB, L2-resident per XCD).
    int bid = blockIdx.x;
    int swz = (bid & 7) * 128 + (bid >> 3);
    const int bm = swz & 63;            // 0..63  (M / 128)
    const int bn = swz >> 6;            // 0..15  (N / 256)

    // ---- staging addressing: chunk c = tid + 256*i; row = c>>2, j = c&3,
    //      k-chunk kc = j ^ ((row>>1)&3)  (invariant per thread across i) ----
    const int rowS = tid >> 2;                       // 0..63
    const int kc0  = (tid & 3) ^ ((tid >> 3) & 3);   // source-side XOR swizzle
    const unsigned short* gA0 = A + (size_t)(bm * 128 + rowS) * IN_F + kc0 * 8;
    const unsigned short* gB0 = B + (size_t)(bn * 256 + rowS) * IN_F + kc0 * 8;

    // ---- read addressing ----
    const int l16 = lane & 15, quad = lane >> 4;
    const int swz16 = ((quad ^ ((l16 >> 1) & 3)) << 4);   // swizzled 16B slot
    const int aBase = l16 * 64 + swz16;
    const int bBase = wn * 4096 + l16 * 64 + swz16;

    f32x4 acc[8][4];
    #pragma unroll
    for (int i = 0; i < 8; ++i)
        #pragma unroll
        for (int j = 0; j < 4; ++j)
            acc[i][j] = (f32x4){0.f, 0.f, 0.f, 0.f};
    bf16x8 af[4];
    bf16x8 bf[4];

    // ---- prologue: stage tile 0, full drain ----
    STAGE_B(0, 0); STAGE_A(0, 0);
    WAIT_VM(0);
    BARRIER(); FENCE();

    // ---- main loop: t = 0..125 (63 pairs) ----
    #pragma unroll 1
    for (int tt = 0; tt < 126; tt += 2) {
        KTILE(0, 0, 1, 1);
        KTILE(1, 1, 1, 1);
        gA0 += 64; gB0 += 64;           // +2 K-tiles
    }
    // ---- t = 126: stages t=127 (dt=1), drains it ----
    KTILE(0, 0, 1, 1);
    // ---- t = 127: no stages, nothing outstanding ----
    KTILE(1, 1, 0, 0);

    // ---- epilogue ----
    const float s = isc[0] * ws2[0];
    #pragma unroll
    for (int M = 0; M < 8; ++M) {
        int r0 = bm * 128 + M * 16 + quad * 4;
        #pragma unroll
        for (int n = 0; n < 4; ++n) {
            int col = bn * 256 + wn * 64 + n * 16 + l16;
            float* cp = C + (size_t)r0 * OUT_F + col;
            #pragma unroll
            for (int r = 0; r < 4; ++r)
                cp[(size_t)r * OUT_F] = acc[M][n][r] * s;
        }
    }
}

// ---------------- launcher -------------------------------------------------
extern "C" void kernel_launch(void* const* d_in, const int* in_sizes, int n_in,
                              void* d_out, int out_size, void* d_ws, size_t ws_size,
                              hipStream_t stream) {
    const float* x   = (const float*)d_in[0];   // [8192, 4096] fp32
    const int*   wq  = (const int*)d_in[1];     // [4096, 2048] packed fp4 pairs
    const int*   wsb = (const int*)d_in[2];     // [4096, 256] e4m3 bits
    const float* ws2 = (const float*)d_in[3];   // scalar
    const float* isc = (const float*)d_in[4];   // scalar
    float* out = (float*)d_out;                 // [8192, 4096] fp32

    unsigned short* Aq = (unsigned short*)d_ws;                          // 64 MB
    unsigned short* Wd = (unsigned short*)d_ws + (size_t)MROWS * IN_F;   // 32 MB

    static int attr_done = 0;
    if (!attr_done) {
        hipFuncSetAttribute(reinterpret_cast<const void*>(gemm128x256),
                            hipFuncAttributeMaxDynamicSharedMemorySize, 49152);
        attr_done = 1;
    }

    quant_act_kernel<<<32768, 256, 0, stream>>>(x, isc, Aq);
    dequant_w_kernel<<<8192, 256, 0, stream>>>(wq, wsb, Wd);
    // 64 x 16 = 1024 blocks of 256 threads; 48 KiB dynamic LDS
    gemm128x256<<<1024, 256, 49152, stream>>>(Aq, Wd, out, isc, ws2);

    (void)in_sizes; (void)n_in; (void)out_size; (void)ws_size;
}